// Round 1
// baseline (125.624 us; speedup 1.0000x reference)
//
#include <hip/hip_runtime.h>
#include <cmath>

// Problem constants (fixed by the reference setup)
constexpr int T = 2048;
constexpr int B = 8;
constexpr int C = 1024;
constexpr int H = 16;
constexpr int K = 31;
constexpr int PAD = 15;          // PADDING_L
constexpr int NBC = B * C;       // 8192, contiguous (b,c) stride between t rows
constexpr int TT = 32;           // t-outputs per thread
constexpr int BLOCK = 256;

__device__ __forceinline__ float uniform_f(float v) {
    return __int_as_float(__builtin_amdgcn_readfirstlane(__float_as_int(v)));
}

__global__ __launch_bounds__(BLOCK) void lconv_tbc_kernel(
    const float* __restrict__ x,      // (T, B, C)
    const float* __restrict__ wgt,    // (H, 1, K)
    const float* __restrict__ bias,   // (C)
    float* __restrict__ out)          // (T, B, C)
{
    const int tid  = threadIdx.x;
    const int wave = tid >> 6;
    const int lane = tid & 63;
    const int bc   = blockIdx.x * BLOCK + tid;   // 0..NBC-1, contiguous per wave
    const int c    = bc & (C - 1);
    const int t0   = blockIdx.y * TT;

    // ---- per-wave softmax of this wave's head kernel (wave covers exactly one head) ----
    __shared__ float sw[BLOCK / 64][K];
    {
        const int c0   = (blockIdx.x * BLOCK + wave * 64) & (C - 1);
        const int head = c0 >> 6;    // R = C/H = 64 channels share one head kernel
        float raw = (lane < K) ? wgt[head * K + lane] : -INFINITY;
        float m = raw;
        #pragma unroll
        for (int off = 32; off >= 1; off >>= 1) m = fmaxf(m, __shfl_xor(m, off));
        float e = (lane < K) ? expf(raw - m) : 0.0f;
        float s = e;
        #pragma unroll
        for (int off = 32; off >= 1; off >>= 1) s += __shfl_xor(s, off);
        if (lane < K) sw[wave][lane] = e / s;
    }
    __syncthreads();

    // Wave-uniform taps -> SGPRs via readfirstlane (saves ~31 VGPRs; v_fmac takes 1 sgpr src)
    float w[K];
    #pragma unroll
    for (int k = 0; k < K; ++k) w[k] = uniform_f(sw[wave][k]);

    // ---- load TT + K - 1 input values for this column into registers ----
    const int tstart = t0 - PAD;
    float xv[TT + K - 1];
    if (t0 >= PAD && t0 + TT + PAD <= T) {
        // interior tile: no bounds checks
        const float* xp = x + (size_t)tstart * NBC + bc;
        #pragma unroll
        for (int j = 0; j < TT + K - 1; ++j)
            xv[j] = xp[(size_t)j * NBC];
    } else {
        #pragma unroll
        for (int j = 0; j < TT + K - 1; ++j) {
            const int tg = tstart + j;
            xv[j] = (tg >= 0 && tg < T) ? x[(size_t)tg * NBC + bc] : 0.0f;
        }
    }

    // ---- cross-correlation: out[t0+i] = sum_k w[k] * x[t0+i+k-PAD] ----
    float acc[TT];
    #pragma unroll
    for (int i = 0; i < TT; ++i) acc[i] = 0.0f;

    #pragma unroll
    for (int j = 0; j < TT + K - 1; ++j) {
        const float v = xv[j];
        #pragma unroll
        for (int i = 0; i < TT; ++i) {
            const int k = j - i;        // compile-time per (i,j)
            if (k >= 0 && k < K)
                acc[i] = fmaf(w[k], v, acc[i]);
        }
    }

    // ---- epilogue: bias + coalesced stores ----
    const float bb = bias[c];
    float* op = out + (size_t)t0 * NBC + bc;
    #pragma unroll
    for (int i = 0; i < TT; ++i)
        op[(size_t)i * NBC] = acc[i] + bb;
}

extern "C" void kernel_launch(void* const* d_in, const int* in_sizes, int n_in,
                              void* d_out, int out_size, void* d_ws, size_t ws_size,
                              hipStream_t stream) {
    const float* x    = (const float*)d_in[0];
    const float* wgt  = (const float*)d_in[1];
    const float* bias = (const float*)d_in[2];
    float* out        = (float*)d_out;

    dim3 grid(NBC / BLOCK, T / TT);   // (32, 64) = 2048 blocks
    lconv_tbc_kernel<<<grid, dim3(BLOCK), 0, stream>>>(x, wgt, bias, out);
}

// Round 2
// 111.699 us; speedup vs baseline: 1.1247x; 1.1247x over previous
//
#include <hip/hip_runtime.h>
#include <cmath>

// Problem constants (fixed by the reference setup)
constexpr int T = 2048;
constexpr int B = 8;
constexpr int C = 1024;
constexpr int H = 16;
constexpr int K = 31;
constexpr int PAD = 15;            // PADDING_L
constexpr int NBC = B * C;         // 8192 = contiguous (b,c) extent; t-stride in elements
constexpr int BC_TILE = 64;        // columns per block == R (one head per block)
constexpr int T_TILE = 128;        // t-outputs per block
constexpr int ROWS = T_TILE + K - 1;   // 158 staged rows (incl. halo)
constexpr int BLOCK = 256;         // 4 waves
constexpr int WAVES = BLOCK / 64;
constexpr int TT = T_TILE / WAVES; // 32 t-outputs per thread

__device__ __forceinline__ float uniform_f(float v) {
    return __int_as_float(__builtin_amdgcn_readfirstlane(__float_as_int(v)));
}

// async global->LDS, 4 bytes/lane: LDS dest = base + lane*4 (linear row),
// global src is per-lane.
__device__ __forceinline__ void gld_lds_b32(const float* gsrc, float* ldst) {
    __builtin_amdgcn_global_load_lds(
        (const __attribute__((address_space(1))) unsigned int*)gsrc,
        (__attribute__((address_space(3))) unsigned int*)ldst,
        4, 0, 0);
}

__global__ __launch_bounds__(BLOCK, 1) void lconv_tbc_kernel(
    const float* __restrict__ x,      // (T, B, C)
    const float* __restrict__ wgt,    // (H, 1, K)
    const float* __restrict__ bias,   // (C)
    float* __restrict__ out)          // (T, B, C)
{
    __shared__ float xs[ROWS * BC_TILE];   // 158 x 64 floats = 40448 B
    __shared__ float sw[K];

    const int tid  = threadIdx.x;
    const int wave = tid >> 6;
    const int lane = tid & 63;
    const int bc0  = blockIdx.x * BC_TILE;      // aligned to head boundary
    const int t0   = blockIdx.y * T_TILE;
    const int tstart = t0 - PAD;

    // ---- stage x tile into LDS (fire-and-forget; one 256B row per instr) ----
    for (int r = wave; r < ROWS; r += WAVES) {
        const int tg = tstart + r;
        if (tg >= 0 && tg < T) {
            gld_lds_b32(x + (size_t)tg * NBC + bc0 + lane, &xs[r * BC_TILE]);
        } else {
            xs[r * BC_TILE + lane] = 0.0f;   // halo rows outside [0,T)
        }
    }

    // ---- per-block softmax of this head's 31 taps (wave 0 only) ----
    if (wave == 0) {
        const int head = (bc0 & (C - 1)) >> 6;   // R = 64 channels share a head
        float raw = (lane < K) ? wgt[head * K + lane] : -INFINITY;
        float m = raw;
        #pragma unroll
        for (int off = 32; off >= 1; off >>= 1) m = fmaxf(m, __shfl_xor(m, off));
        float e = (lane < K) ? expf(raw - m) : 0.0f;
        float s = e;
        #pragma unroll
        for (int off = 32; off >= 1; off >>= 1) s += __shfl_xor(s, off);
        if (lane < K) sw[lane] = e / s;
    }

    __syncthreads();   // drains vmcnt (gld_lds) + lgkmcnt, then barrier

    // taps -> SGPRs (wave-uniform; v_fmac takes one scalar operand)
    float w[K];
    #pragma unroll
    for (int k = 0; k < K; ++k) w[k] = uniform_f(sw[k]);

    // ---- compute: thread = (column lane, t-slice wave), stream LDS rows ----
    float acc[TT];
    #pragma unroll
    for (int i = 0; i < TT; ++i) acc[i] = 0.0f;

    const float* xrow = &xs[(wave * TT) * BC_TILE + lane];
    #pragma unroll
    for (int j = 0; j < TT + K - 1; ++j) {
        const float v = xrow[(size_t)j * BC_TILE];   // 64 lanes stride-1: conflict-free
        #pragma unroll
        for (int i = 0; i < TT; ++i) {
            const int k = j - i;                     // compile-time per (i,j)
            if (k >= 0 && k < K)
                acc[i] = fmaf(w[k], v, acc[i]);
        }
    }

    // ---- epilogue: bias + coalesced 256B/wave stores ----
    const int c = (bc0 + lane) & (C - 1);
    const float bb = bias[c];
    float* op = out + (size_t)(t0 + wave * TT) * NBC + bc0 + lane;
    #pragma unroll
    for (int i = 0; i < TT; ++i)
        op[(size_t)i * NBC] = acc[i] + bb;
}

extern "C" void kernel_launch(void* const* d_in, const int* in_sizes, int n_in,
                              void* d_out, int out_size, void* d_ws, size_t ws_size,
                              hipStream_t stream) {
    const float* x    = (const float*)d_in[0];
    const float* wgt  = (const float*)d_in[1];
    const float* bias = (const float*)d_in[2];
    float* out        = (float*)d_out;

    dim3 grid(NBC / BC_TILE, T / T_TILE);   // (128, 16) = 2048 blocks
    lconv_tbc_kernel<<<grid, dim3(BLOCK), 0, stream>>>(x, wgt, bias, out);
}

// Round 3
// 37.967 us; speedup vs baseline: 3.3088x; 2.9420x over previous
//
#include <hip/hip_runtime.h>
#include <utility>
#include <cmath>

// Problem constants (fixed by the reference setup)
constexpr int T = 2048;
constexpr int B = 8;
constexpr int C = 1024;
constexpr int H = 16;
constexpr int K = 31;
constexpr int PAD = 15;              // PADDING_L
constexpr int NBC = B * C;           // 8192 = t-stride in elements; (b,c) contiguous
constexpr int BC_TILE = 64;          // columns per block == R (one head per block)
constexpr int T_TILE = 64;           // t-outputs per block
constexpr int ROWS = T_TILE + K - 1; // 94 staged rows incl. halo
constexpr int BLOCK = 256;           // 4 waves
constexpr int WAVES = BLOCK / 64;
constexpr int TT = T_TILE / WAVES;   // 16 t-outputs per thread
constexpr int WIN = TT + K - 1;      // 46 register window

__device__ __forceinline__ float uniform_f(float v) {
    return __int_as_float(__builtin_amdgcn_readfirstlane(__float_as_int(v)));
}

__device__ __forceinline__ void gld_lds_b32(const float* gsrc, float* ldst) {
    __builtin_amdgcn_global_load_lds(
        (const __attribute__((address_space(1))) unsigned int*)gsrc,
        (__attribute__((address_space(3))) unsigned int*)ldst,
        4, 0, 0);
}

// One tap: KK is a compile-time constant -> w[KK] stays in an SGPR,
// xv[i+KK] is a statically-indexed register. No dynamic array indexing anywhere.
template <int KK>
__device__ __forceinline__ void tap(float (&acc)[TT], const float (&xv)[WIN], float wk) {
#pragma unroll
    for (int i = 0; i < TT; ++i)
        acc[i] = fmaf(wk, xv[i + KK], acc[i]);
}

template <int... Ks>
__device__ __forceinline__ void all_taps(float (&acc)[TT], const float (&xv)[WIN],
                                         const float (&w)[K],
                                         std::integer_sequence<int, Ks...>) {
    (tap<Ks>(acc, xv, w[Ks]), ...);
}

__global__ __launch_bounds__(BLOCK, 6) void lconv_tbc_kernel(
    const float* __restrict__ x,      // (T, B, C)
    const float* __restrict__ wgt,    // (H, 1, K)
    const float* __restrict__ bias,   // (C)
    float* __restrict__ out)          // (T, B, C)
{
    __shared__ float xs[ROWS * BC_TILE];   // 94 x 64 floats = 24064 B
    __shared__ float sw[K];

    const int tid  = threadIdx.x;
    const int wave = tid >> 6;
    const int lane = tid & 63;
    const int bc0  = blockIdx.x * BC_TILE;      // head-aligned
    const int t0   = blockIdx.y * T_TILE;
    const int tstart = t0 - PAD;

    // ---- stage x tile into LDS (fire-and-forget, 256B linear rows) ----
    for (int r = wave; r < ROWS; r += WAVES) {
        const int tg = tstart + r;
        if (tg >= 0 && tg < T) {
            gld_lds_b32(x + (size_t)tg * NBC + bc0 + lane, &xs[r * BC_TILE]);
        } else {
            xs[r * BC_TILE + lane] = 0.0f;
        }
    }

    // ---- per-block softmax of this head's 31 taps ----
    if (wave == 0) {
        const int head = (bc0 & (C - 1)) >> 6;
        float raw = (lane < K) ? wgt[head * K + lane] : -INFINITY;
        float m = raw;
        #pragma unroll
        for (int off = 32; off >= 1; off >>= 1) m = fmaxf(m, __shfl_xor(m, off));
        float e = (lane < K) ? expf(raw - m) : 0.0f;
        float s = e;
        #pragma unroll
        for (int off = 32; off >= 1; off >>= 1) s += __shfl_xor(s, off);
        if (lane < K) sw[lane] = e / s;
    }

    __syncthreads();   // drains gld_lds (vmcnt) + lgkm, then barrier

    // taps -> wave-uniform SGPRs
    float w[K];
    #pragma unroll
    for (int k = 0; k < K; ++k) w[k] = uniform_f(sw[k]);

    // ---- per-thread register window: 46 statically-indexed LDS reads ----
    float xv[WIN];
    const float* xrow = &xs[(wave * TT) * BC_TILE + lane];
    #pragma unroll
    for (int j = 0; j < WIN; ++j)
        xv[j] = xrow[j * BC_TILE];     // base + j*256B immediate offsets

    float acc[TT];
    #pragma unroll
    for (int i = 0; i < TT; ++i) acc[i] = 0.0f;

    // ---- 31 x 16 FMAs, every index compile-time by construction ----
    all_taps(acc, xv, w, std::make_integer_sequence<int, K>{});

    // ---- epilogue: bias + coalesced 256B/wave stores ----
    const int c = (bc0 + lane) & (C - 1);
    const float bb = bias[c];
    float* op = out + (size_t)(t0 + wave * TT) * NBC + bc0 + lane;
    #pragma unroll
    for (int i = 0; i < TT; ++i)
        op[(size_t)i * NBC] = acc[i] + bb;
}

extern "C" void kernel_launch(void* const* d_in, const int* in_sizes, int n_in,
                              void* d_out, int out_size, void* d_ws, size_t ws_size,
                              hipStream_t stream) {
    const float* x    = (const float*)d_in[0];
    const float* wgt  = (const float*)d_in[1];
    const float* bias = (const float*)d_in[2];
    float* out        = (float*)d_out;

    dim3 grid(NBC / BC_TILE, T / T_TILE);   // (128, 32) = 4096 blocks
    lconv_tbc_kernel<<<grid, dim3(BLOCK), 0, stream>>>(x, wgt, bias, out);
}